// Round 3
// baseline (2560.316 us; speedup 1.0000x reference)
//
#include <hip/hip_runtime.h>
#include <math.h>

#define NPTS 4096
#define NCH  1024
#define HH 128
#define WW 128
#define SLICE (HH*WW)
#define PARTW 2048

struct WsPtrs {
  double* Hg;      // 27 doubles: H upper-tri (21) then g (6)
  float* state;    // [0..8]=R,[9..11]=t,[12]=lam,[13]=prev_cost,[14..22]=R_new,[23..25]=t_new
  float* p3d0;     // 3*NPTS SoA
  float* idx0x;    // NPTS (fallback path)
  float* idx0y;    // NPTS
  float* nidxx;    // NPTS clipped sample x at tentative state
  float* nidxy;    // NPTS
  float* np2;      // 2*NPTS interleaved
  float* best;     // 2*NPTS interleaved
  float* P12;      // 12*NPTS: per point r0[6], r1[6]
  float* coef;     // NPTS*16 float4: (wf, wgx, wgy, bitcast(pixel))
  float* part;     // 28*PARTW per-block partials
  float* feat0;    // [NCH][NPTS]
  float* feat0t;   // [NPTS][NCH]
  float* img1t;    // [SLICE][NCH]
};

// ---- per-point: project, store np2/nidx/P12, build 16 sampling coefficients ----
__device__ inline void build_point(int n, const float* sRt, float fx, float fy,
                                   float cx, float cy, float px, float py, float pz,
                                   WsPtrs& ws, float* scr /*48 floats LDS scratch*/)
{
  float X = sRt[0]*px + sRt[1]*py + sRt[2]*pz + sRt[9];
  float Y = sRt[3]*px + sRt[4]*py + sRt[5]*pz + sRt[10];
  float Z = sRt[6]*px + sRt[7]*py + sRt[8]*pz + sRt[11];
  float p2x = (fx*X + cx*Z)/Z;
  float p2y = (fy*Y + cy*Z)/Z;
  ws.np2[2*n]=p2x; ws.np2[2*n+1]=p2y;
  float xx = fminf(fmaxf(p2x*0.125f,0.f),(float)(WW-1));
  float yy = fminf(fmaxf(p2y*0.125f,0.f),(float)(HH-1));
  ws.nidxx[n]=xx; ws.nidxy[n]=yy;
  float a = (fx/Z)*0.125f;
  float b = (fy/Z)*0.125f;
  float c = ((-fx*X)/Z)/Z*0.125f;
  float d = ((-fy*Y)/Z)/Z*0.125f;
  // J rows through [I | -skew(p3)]
  float r0[6] = {a, 0.f, c, c*Y, a*Z - c*X, -a*Y};
  float r1[6] = {0.f, b, d, d*Y - b*Z, -d*X, b*X};
  #pragma unroll
  for (int k=0;k<6;k++){ ws.P12[n*12+k]=r0[k]; ws.P12[n*12+6+k]=r1[k]; }
  // sampling coefficients over the 4x4 window
  float x0f=floorf(xx), y0f=floorf(yy);
  float wx=xx-x0f, wy=yy-y0f;
  int xi=(int)x0f, yi=(int)y0f;
  int x1c=min(xi+1,WW-1), y1c=min(yi+1,HH-1);
  float w00=(1.f-wx)*(1.f-wy), w10=wx*(1.f-wy), w01=(1.f-wx)*wy, w11=wx*wy;
  float* wf = scr; float* wgx = scr+16; float* wgy = scr+32;
  for (int p=0;p<48;p++) scr[p]=0.f;
  int c1 = x1c-(xi-1);   // window col of clamped x1 (1 or 2)
  int rr1 = y1c-(yi-1);  // window row of clamped y1 (1 or 2)
  wf[4+1]      += w00;
  wf[4+c1]     += w10;
  wf[rr1*4+1]  += w01;
  wf[rr1*4+c1] += w11;
  const float kxv[9] = {-0.125f,0.f,0.125f, -0.25f,0.f,0.25f, -0.125f,0.f,0.125f};
  const float kyv[9] = {-0.125f,-0.25f,-0.125f, 0.f,0.f,0.f, 0.125f,0.25f,0.125f};
  int cys[4]={yi,yi,y1c,y1c}, cxs[4]={xi,x1c,xi,x1c};
  float cwv[4]={w00,w10,w01,w11};
  for (int corner=0;corner<4;corner++){
    int cy0=cys[corner], cx0=cxs[corner]; float w=cwv[corner];
    for (int dy=0;dy<3;dy++){
      int sy=cy0+dy-1; if (sy<0||sy>=HH) continue;
      for (int dx=0;dx<3;dx++){
        int sx=cx0+dx-1; if (sx<0||sx>=WW) continue;
        int slot=(sy-(yi-1))*4 + (sx-(xi-1));
        wgx[slot] += w*kxv[dy*3+dx];
        wgy[slot] += w*kyv[dy*3+dx];
      }
    }
  }
  float4* cp = ((float4*)ws.coef) + (size_t)n*16;
  #pragma unroll
  for (int p=0;p<16;p++){
    int r=p>>2, cc2=p&3;
    int ay=min(max(yi-1+r,0),HH-1), ax=min(max(xi-1+cc2,0),WW-1);
    float4 cf; cf.x=wf[p]; cf.y=wgx[p]; cf.z=wgy[p]; cf.w=__int_as_float(ay*WW+ax);
    cp[p]=cf;
  }
}

// ---- init kernel ----
__global__ __launch_bounds__(256) void prep_init_kernel(
    const float* __restrict__ pts2d, const float* __restrict__ pts3d,
    const float* __restrict__ qm, const float* __restrict__ rm,
    const float* __restrict__ K1, WsPtrs ws)
{
  __shared__ float sRt[12];
  __shared__ float cscratch[256*48];
  const int t = threadIdx.x;
  if (t == 0) {
    double M[4][8];
    for (int i=0;i<4;i++) for (int j=0;j<4;j++){ M[i][j]=rm[i*4+j]; M[i][4+j]=(i==j)?1.0:0.0; }
    for (int k=0;k<4;k++){
      int p=k; double bv=fabs(M[k][k]);
      for (int i=k+1;i<4;i++){ double v=fabs(M[i][k]); if(v>bv){bv=v;p=i;} }
      if (p!=k) for (int j=0;j<8;j++){ double tmp=M[k][j]; M[k][j]=M[p][j]; M[p][j]=tmp; }
      double pv = M[k][k];
      for (int j=0;j<8;j++) M[k][j] /= pv;
      for (int i=0;i<4;i++) if (i!=k){
        double f2=M[i][k];
        for (int j=0;j<8;j++) M[i][j] -= f2*M[k][j];
      }
    }
    float rel[16];
    for (int i=0;i<4;i++) for (int j=0;j<4;j++){
      float s=0.f;
      for (int k=0;k<4;k++) s += qm[i*4+k]*(float)M[k][4+j];
      rel[i*4+j]=s;
    }
    for (int i=0;i<3;i++) for (int j=0;j<3;j++){ ws.state[i*3+j]=rel[i*4+j]; ws.state[14+i*3+j]=rel[i*4+j]; sRt[i*3+j]=rel[i*4+j]; }
    for (int i=0;i<3;i++){ ws.state[9+i]=rel[i*4+3]; ws.state[23+i]=rel[i*4+3]; sRt[9+i]=rel[i*4+3]; }
    ws.state[12] = 0.01f;
  }
  __syncthreads();
  const float fx=K1[0], cx=K1[2], fy=K1[4], cy=K1[5];
  for (int i=0;i<16;i++){
    int n = t + i*256;
    float X=pts3d[n*3+0], Y=pts3d[n*3+1], Z=pts3d[n*3+2];
    float hx = rm[0]*X + rm[1]*Y + rm[2]*Z + rm[3];
    float hy = rm[4]*X + rm[5]*Y + rm[6]*Z + rm[7];
    float hz = rm[8]*X + rm[9]*Y + rm[10]*Z + rm[11];
    float hw = rm[12]*X + rm[13]*Y + rm[14]*Z + rm[15];
    float px = hx/hw, py = hy/hw, pz = hz/hw;
    ws.p3d0[n]=px; ws.p3d0[NPTS+n]=py; ws.p3d0[2*NPTS+n]=pz;
    ws.idx0x[n]=pts2d[n*2+0]*0.125f;
    ws.idx0y[n]=pts2d[n*2+1]*0.125f;
    build_point(n, sRt, fx, fy, cx, cy, px, py, pz, ws, cscratch + t*48);
  }
}

// ---- feat0 (iteration-invariant): one block per channel, writes [c][n] ----
__global__ __launch_bounds__(256) void feat0_kernel(
    const float* __restrict__ img0, const float* __restrict__ pts2d, WsPtrs ws)
{
  __shared__ __align__(16) float tile[SLICE];
  const int c = blockIdx.x;
  const int t = threadIdx.x;
  {
    const float4* g4 = reinterpret_cast<const float4*>(img0 + (size_t)c*SLICE);
    float4* t4 = reinterpret_cast<float4*>(tile);
    #pragma unroll
    for (int i=0;i<16;i++) t4[t + i*256] = g4[t + i*256];
  }
  __syncthreads();
  #pragma unroll
  for (int i=0;i<16;i++){
    int n = t + i*256;
    float x = pts2d[n*2+0]*0.125f, y = pts2d[n*2+1]*0.125f;
    float x0f=floorf(x), y0f=floorf(y);
    float wx=x-x0f, wy=y-y0f;
    int xi=min(max((int)x0f,0),WW-1);
    int yi=min(max((int)y0f,0),HH-1);
    int x1=min(xi+1,WW-1), y1=min(yi+1,HH-1);
    float f00=tile[yi*WW+xi], f10=tile[yi*WW+x1], f01=tile[y1*WW+xi], f11=tile[y1*WW+x1];
    ws.feat0[(size_t)c*NPTS + n] =
      f00*(1.f-wx)*(1.f-wy) + f10*wx*(1.f-wy) + f01*(1.f-wx)*wy + f11*wx*wy;
  }
}

// ---- generic 32x32 tiled transpose: src[R][Cc] -> dst[Cc][R] ----
__global__ __launch_bounds__(256) void transpose_kernel(
    const float* __restrict__ src, float* __restrict__ dst, int R, int Cc)
{
  __shared__ float tile[32][33];
  int bx = blockIdx.x*32, by = blockIdx.y*32;
  int tx = threadIdx.x & 31, ty = threadIdx.x >> 5;
  #pragma unroll
  for (int k=0;k<4;k++){
    int r = by + ty + k*8;
    tile[ty + k*8][tx] = src[(size_t)r*Cc + bx + tx];
  }
  __syncthreads();
  #pragma unroll
  for (int k=0;k<4;k++){
    int r = bx + ty + k*8;
    dst[(size_t)r*R + by + tx] = tile[tx][ty + k*8];
  }
}

// ---- main pass (fast path): 2 points per block, streaming coalesced gather ----
__global__ __launch_bounds__(256) void big_kernel(
    const float* __restrict__ img1t, const float* __restrict__ f0t, WsPtrs ws)
{
  __shared__ float4 scoef[2][16];
  __shared__ float sr[2][12];
  __shared__ float red6[4][6];
  __shared__ float sh6[6];
  const int b = blockIdx.x, t = threadIdx.x;
  const int n0 = b*2;
  if (t < 32) scoef[t>>4][t&15] = ((const float4*)ws.coef)[(size_t)n0*16 + t];
  else if (t < 56) { int q = t-32; sr[q/12][q%12] = ws.P12[(size_t)n0*12 + q]; }
  int kk=0, ll=0;
  if (t < 21){ int rem=t, k=0; while (rem >= 6-k){ rem -= 6-k; k++; } kk=k; ll=k+rem; }
  __syncthreads();
  float part28 = 0.f;
  const float* ip = img1t + 4*t;
  #pragma unroll
  for (int pt=0; pt<2; pt++){
    const int n = n0 + pt;
    float f10=0.f,f11=0.f,f12=0.f,f13=0.f;
    float gx0=0.f,gx1=0.f,gx2=0.f,gx3=0.f;
    float gy0=0.f,gy1=0.f,gy2=0.f,gy3=0.f;
    #pragma unroll
    for (int p=0;p<16;p++){
      float4 cf = scoef[pt][p];
      int pix = __float_as_int(cf.w);
      float4 v = *(const float4*)(ip + ((size_t)pix<<10));
      f10 = fmaf(cf.x, v.x, f10); f11 = fmaf(cf.x, v.y, f11);
      f12 = fmaf(cf.x, v.z, f12); f13 = fmaf(cf.x, v.w, f13);
      gx0 = fmaf(cf.y, v.x, gx0); gx1 = fmaf(cf.y, v.y, gx1);
      gx2 = fmaf(cf.y, v.z, gx2); gx3 = fmaf(cf.y, v.w, gx3);
      gy0 = fmaf(cf.z, v.x, gy0); gy1 = fmaf(cf.z, v.y, gy1);
      gy2 = fmaf(cf.z, v.z, gy2); gy3 = fmaf(cf.z, v.w, gy3);
    }
    float4 f0 = *(const float4*)(f0t + ((size_t)n<<10) + 4*t);
    float e0=f10-f0.x, e1=f11-f0.y, e2=f12-f0.z, e3=f13-f0.w;
    float v6[6];
    v6[0] = gx0*gx0 + gx1*gx1 + gx2*gx2 + gx3*gx3;            // m0 = sum gx^2
    v6[1] = gx0*gy0 + gx1*gy1 + gx2*gy2 + gx3*gy3;            // m1 = sum gx*gy
    v6[2] = gy0*gy0 + gy1*gy1 + gy2*gy2 + gy3*gy3;            // m2 = sum gy^2
    v6[3] = e0*gx0 + e1*gx1 + e2*gx2 + e3*gx3;                // s0 = sum e*gx
    v6[4] = e0*gy0 + e1*gy1 + e2*gy2 + e3*gy3;                // s1 = sum e*gy
    v6[5] = e0*e0 + e1*e1 + e2*e2 + e3*e3;                    // ss = sum e^2
    #pragma unroll
    for (int j=0;j<6;j++){
      float vv=v6[j];
      for (int off=32; off>0; off>>=1) vv += __shfl_down(vv, off, 64);
      v6[j]=vv;
    }
    int wave=t>>6, lane=t&63;
    if (lane==0){
      #pragma unroll
      for (int j=0;j<6;j++) red6[wave][j]=v6[j];
    }
    __syncthreads();
    if (t<6) sh6[t] = red6[0][t]+red6[1][t]+red6[2][t]+red6[3][t];
    __syncthreads();
    if (t<28){
      float m0=sh6[0], m1=sh6[1], m2=sh6[2], s0=sh6[3], s1=sh6[4], ss=sh6[5];
      const float* r0 = sr[pt];
      const float* r1 = sr[pt]+6;
      float ev;
      if (t<21)      ev = m0*r0[kk]*r0[ll] + m1*(r0[kk]*r1[ll] + r1[kk]*r0[ll]) + m2*r1[kk]*r1[ll];
      else if (t<27) ev = s0*r0[t-21] + s1*r1[t-21];
      else           ev = ss;
      part28 += ev;
    }
    __syncthreads();
  }
  if (t<28) ws.part[(size_t)t*PARTW + b] = part28;
}

// ---- fallback main pass (ws too small): round-1 proven two-phase ----
__global__ __launch_bounds__(256) void bigfb_kernel(
    const float* __restrict__ img0, const float* __restrict__ img1, WsPtrs ws)
{
  __shared__ __align__(16) float tile[SLICE];
  const int c = blockIdx.x;
  const int t = threadIdx.x;
  {
    const float4* g4 = reinterpret_cast<const float4*>(img1 + (size_t)c*SLICE);
    float4* t4 = reinterpret_cast<float4*>(tile);
    #pragma unroll
    for (int i=0;i<16;i++) t4[t + i*256] = g4[t + i*256];
  }
  __syncthreads();
  float f1a[16], gxa[16], gya[16];
  #pragma unroll
  for (int i=0;i<16;i++){
    int n = t + i*256;
    float x = ws.nidxx[n], y = ws.nidxy[n];
    float x0f = floorf(x), y0f = floorf(y);
    float wx = x - x0f, wy = y - y0f;
    int xi = (int)x0f, yi = (int)y0f;
    float v[4][4];
    if (xi>=1 && xi<=WW-3 && yi>=1 && yi<=HH-3) {
      int base = (yi-1)*WW + (xi-1);
      #pragma unroll
      for (int r=0;r<4;r++)
        #pragma unroll
        for (int cc=0;cc<4;cc++)
          v[r][cc] = tile[base + r*WW + cc];
    } else {
      #pragma unroll
      for (int r=0;r<4;r++){
        int ry = yi-1+r;
        bool okr = (ry>=0) && (ry<HH);
        int ryc = min(max(ry,0),HH-1);
        #pragma unroll
        for (int cc=0;cc<4;cc++){
          int rx = xi-1+cc;
          bool ok = okr && (rx>=0) && (rx<WW);
          int rxc = min(max(rx,0),WW-1);
          float val = tile[ryc*WW + rxc];
          v[r][cc] = ok ? val : 0.f;
        }
      }
    }
    float D1[4], D2[4], E0a[4], E1a[4];
    #pragma unroll
    for (int r=0;r<4;r++){ D1[r]=v[r][2]-v[r][0]; D2[r]=v[r][3]-v[r][1]; }
    #pragma unroll
    for (int cc=0;cc<4;cc++){ E0a[cc]=v[2][cc]-v[0][cc]; E1a[cc]=v[3][cc]-v[1][cc]; }
    float gx00 = D1[0] + 2.f*D1[1] + D1[2];
    float gx01 = D2[0] + 2.f*D2[1] + D2[2];
    float gx10 = D1[1] + 2.f*D1[2] + D1[3];
    float gx11 = D2[1] + 2.f*D2[2] + D2[3];
    float gy00 = E0a[0] + 2.f*E0a[1] + E0a[2];
    float gy01 = E0a[1] + 2.f*E0a[2] + E0a[3];
    float gy10 = E1a[0] + 2.f*E1a[1] + E1a[2];
    float gy11 = E1a[1] + 2.f*E1a[2] + E1a[3];
    float w00=(1.f-wx)*(1.f-wy), w10=wx*(1.f-wy), w01=(1.f-wx)*wy, w11=wx*wy;
    f1a[i] = w00*v[1][1] + w10*v[1][2] + w01*v[2][1] + w11*v[2][2];
    gxa[i] = 0.125f*(w00*gx00 + w10*gx01 + w01*gx10 + w11*gx11);
    gya[i] = 0.125f*(w00*gy00 + w10*gy01 + w01*gy10 + w11*gy11);
  }
  __syncthreads();
  {
    const float4* g4 = reinterpret_cast<const float4*>(img0 + (size_t)c*SLICE);
    float4* t4 = reinterpret_cast<float4*>(tile);
    #pragma unroll
    for (int i=0;i<16;i++) t4[t + i*256] = g4[t + i*256];
  }
  __syncthreads();
  float acc[28];
  #pragma unroll
  for (int a=0;a<28;a++) acc[a]=0.f;
  for (int i=0;i<16;i++){
    int n = t + i*256;
    float x = ws.idx0x[n], y = ws.idx0y[n];
    float x0f=floorf(x), y0f=floorf(y);
    float wx=x-x0f, wy=y-y0f;
    int xi=min(max((int)x0f,0),WW-1);
    int yi=min(max((int)y0f,0),HH-1);
    int x1=min(xi+1,WW-1), y1=min(yi+1,HH-1);
    float f00=tile[yi*WW+xi], f10=tile[yi*WW+x1], f01=tile[y1*WW+xi], f11=tile[y1*WW+x1];
    float feat0 = f00*(1.f-wx)*(1.f-wy) + f10*wx*(1.f-wy) + f01*(1.f-wx)*wy + f11*wx*wy;
    float e = f1a[i] - feat0;
    float gx = gxa[i], gy = gya[i];
    const float* r0 = ws.P12 + (size_t)n*12;
    const float* r1 = r0 + 6;
    float jv[6];
    #pragma unroll
    for (int k=0;k<6;k++) jv[k] = gx*r0[k] + gy*r1[k];
    int p=0;
    #pragma unroll
    for (int k=0;k<6;k++)
      #pragma unroll
      for (int l=k;l<6;l++)
        { acc[p] += jv[k]*jv[l]; p++; }
    #pragma unroll
    for (int k=0;k<6;k++) acc[21+k] += e*jv[k];
    acc[27] += e*e;
  }
  __syncthreads();
  #pragma unroll
  for (int a=0;a<28;a++){
    float vv=acc[a];
    for (int off=32; off>0; off>>=1) vv += __shfl_down(vv, off, 64);
    acc[a]=vv;
  }
  int wave = t>>6, lane = t&63;
  if (lane==0){
    #pragma unroll
    for (int a=0;a<28;a++) tile[wave*28+a]=acc[a];
  }
  __syncthreads();
  if (t<28){
    float s = tile[t]+tile[28+t]+tile[56+t]+tile[84+t];
    ws.part[(size_t)t*PARTW + c] = s;
    ws.part[(size_t)t*PARTW + 1024 + c] = 0.f;
  }
}

// ---- fused commit + LM solve + reprojection + coefficient rebuild ----
__global__ __launch_bounds__(256) void update_kernel(
    int force, const float* __restrict__ K1, WsPtrs ws, float* __restrict__ dout)
{
  const int t = threadIdx.x;
  __shared__ float red[4*28];
  __shared__ double stot[28];
  __shared__ float sRt[12];
  __shared__ int sacc;
  __shared__ float cscratch[256*48];
  float loc[28];
  #pragma unroll
  for (int a=0;a<28;a++){
    const float* pa = ws.part + (size_t)a*PARTW;
    float s=0.f;
    #pragma unroll
    for (int k=0;k<8;k++) s += pa[t + k*256];
    loc[a]=s;
  }
  #pragma unroll
  for (int a=0;a<28;a++){
    float vv=loc[a];
    for (int off=32;off>0;off>>=1) vv += __shfl_down(vv,off,64);
    loc[a]=vv;
  }
  int wave=t>>6, lane=t&63;
  if (lane==0){
    #pragma unroll
    for (int a=0;a<28;a++) red[wave*28+a]=loc[a];
  }
  __syncthreads();
  if (t<28) stot[t] = (double)red[t]+(double)red[28+t]+(double)red[56+t]+(double)red[84+t];
  __syncthreads();
  if (t==0){
    float cost_new = (float)(stot[27] / (double)NPTS);
    int acc = force || (cost_new <= ws.state[13]);
    if (acc){
      ws.state[13]=cost_new;
      for (int k=0;k<9;k++) ws.state[k]=ws.state[14+k];
      for (int k=0;k<3;k++) ws.state[9+k]=ws.state[23+k];
      for (int a=0;a<27;a++) ws.Hg[a]=stot[a];
    }
    if (!force){
      float l = ws.state[12]*(acc?0.1f:10.f);
      ws.state[12]=fminf(fmaxf(l,1e-6f),100.f);
    }
    sacc=acc;
    // LM solve at committed state
    double M[6][7];
    {
      double Hf[6][6]; int p=0;
      for (int k=0;k<6;k++) for (int l=k;l<6;l++){ double v=ws.Hg[p++]; Hf[k][l]=v; Hf[l][k]=v; }
      double lam = (double)ws.state[12];
      for (int k=0;k<6;k++){
        for (int l=0;l<6;l++) M[k][l]=Hf[k][l];
        M[k][6]=ws.Hg[21+k];
      }
      for (int k=0;k<6;k++) M[k][k] = M[k][k] + (M[k][k] + 1e-9)*lam;
    }
    for (int k=0;k<6;k++){
      int pi=k; double bv=fabs(M[k][k]);
      for (int i=k+1;i<6;i++){ double v=fabs(M[i][k]); if(v>bv){bv=v;pi=i;} }
      if (pi!=k) for (int j=k;j<7;j++){ double tmp=M[k][j];M[k][j]=M[pi][j];M[pi][j]=tmp; }
      double pv=M[k][k];
      for (int i=k+1;i<6;i++){
        double f2=M[i][k]/pv;
        for (int j=k;j<7;j++) M[i][j]-=f2*M[k][j];
      }
    }
    double x[6];
    for (int k=5;k>=0;k--){
      double s=M[k][6];
      for (int j=k+1;j<6;j++) s-=M[k][j]*x[j];
      x[k]=s/M[k][k];
    }
    float dt0=(float)(-x[0]), dt1=(float)(-x[1]), dt2=(float)(-x[2]);
    float w0=(float)(-x[3]), w1=(float)(-x[4]), w2=(float)(-x[5]);
    float th2 = w0*w0+w1*w1+w2*w2;
    float th = sqrtf(fmaxf(th2, 1e-24f));
    float A_ = (th2 < 1e-16f) ? 1.f : (sinf(th)/th);
    float B_ = (th2 < 1e-16f) ? 0.5f : ((1.f - cosf(th)) / fmaxf(th2, 1e-24f));
    float Kx[9] = {0.f,-w2,w1,  w2,0.f,-w0,  -w1,w0,0.f};
    float K2[9];
    for (int i=0;i<3;i++) for (int j=0;j<3;j++){
      float s=0.f; for (int k=0;k<3;k++) s+=Kx[i*3+k]*Kx[k*3+j];
      K2[i*3+j]=s;
    }
    float dr[9];
    for (int i=0;i<9;i++) dr[i] = ((i%4==0)?1.f:0.f) + A_*Kx[i] + B_*K2[i];
    float Rn[9], tn[3];
    for (int i=0;i<3;i++) for (int j=0;j<3;j++){
      float s=0.f; for (int k=0;k<3;k++) s+=dr[i*3+k]*ws.state[k*3+j];
      Rn[i*3+j]=s;
    }
    for (int i=0;i<3;i++){
      float s=0.f; for (int k=0;k<3;k++) s+=dr[i*3+k]*ws.state[9+k];
      tn[i]=s+((i==0)?dt0:(i==1)?dt1:dt2);
    }
    for (int k=0;k<9;k++){ ws.state[14+k]=Rn[k]; sRt[k]=Rn[k]; }
    for (int k=0;k<3;k++){ ws.state[23+k]=tn[k]; sRt[9+k]=tn[k]; }
  }
  __syncthreads();
  // best/out must read np2 of the just-scored tentative BEFORE reprojection
  {
    int acc=sacc;
    float2* best2=(float2*)ws.best;
    const float2* np22=(const float2*)ws.np2;
    float2* out2=(float2*)dout;
    #pragma unroll
    for (int i=0;i<16;i++){
      int n=t+i*256;
      if (acc) best2[n]=np22[n];
      out2[n]=best2[n];
    }
  }
  __syncthreads();
  const float fx=K1[0], cx=K1[2], fy=K1[4], cy=K1[5];
  for (int i=0;i<16;i++){
    int n=t+i*256;
    build_point(n, sRt, fx, fy, cx, cy,
                ws.p3d0[n], ws.p3d0[NPTS+n], ws.p3d0[2*NPTS+n], ws, cscratch + t*48);
  }
}

extern "C" void kernel_launch(void* const* d_in, const int* in_sizes, int n_in,
                              void* d_out, int out_size, void* d_ws, size_t ws_size,
                              hipStream_t stream) {
  (void)in_sizes; (void)n_in; (void)out_size;
  const float* img0  = (const float*)d_in[0];
  const float* img1  = (const float*)d_in[1];
  const float* pts2d = (const float*)d_in[2];
  const float* pts3d = (const float*)d_in[3];
  const float* qm    = (const float*)d_in[4];
  const float* rm    = (const float*)d_in[5];
  const float* K1    = (const float*)d_in[6];
  float* out = (float*)d_out;

  char* w = (char*)d_ws;
  WsPtrs ws;
  ws.Hg    = (double*)w;
  ws.state = (float*)(w + 256);
  float* f = (float*)(w + 512);
  ws.p3d0  = f; f += 3*NPTS;
  ws.idx0x = f; f += NPTS;
  ws.idx0y = f; f += NPTS;
  ws.nidxx = f; f += NPTS;
  ws.nidxy = f; f += NPTS;
  ws.np2   = f; f += 2*NPTS;
  ws.best  = f; f += 2*NPTS;
  ws.P12   = f; f += 12*NPTS;
  ws.coef  = f; f += 64*NPTS;
  ws.part  = f; f += 28*PARTW;
  ws.feat0  = f; f += (size_t)NCH*NPTS;
  ws.feat0t = f; f += (size_t)NCH*NPTS;
  ws.img1t  = f; f += (size_t)NCH*SLICE;
  size_t need = ((char*)f) - w;
  bool fast = (ws_size >= need);

  prep_init_kernel<<<1,256,0,stream>>>(pts2d, pts3d, qm, rm, K1, ws);
  if (fast) {
    feat0_kernel<<<NCH,256,0,stream>>>(img0, pts2d, ws);
    transpose_kernel<<<dim3(NPTS/32, NCH/32),256,0,stream>>>(ws.feat0, ws.feat0t, NCH, NPTS);
    transpose_kernel<<<dim3(SLICE/32, NCH/32),256,0,stream>>>(img1, ws.img1t, NCH, SLICE);
    big_kernel<<<PARTW,256,0,stream>>>(ws.img1t, ws.feat0t, ws);
    update_kernel<<<1,256,0,stream>>>(1, K1, ws, out);
    for (int it=0; it<10; ++it){
      big_kernel<<<PARTW,256,0,stream>>>(ws.img1t, ws.feat0t, ws);
      update_kernel<<<1,256,0,stream>>>(0, K1, ws, out);
    }
  } else {
    bigfb_kernel<<<NCH,256,0,stream>>>(img0, img1, ws);
    update_kernel<<<1,256,0,stream>>>(1, K1, ws, out);
    for (int it=0; it<10; ++it){
      bigfb_kernel<<<NCH,256,0,stream>>>(img0, img1, ws);
      update_kernel<<<1,256,0,stream>>>(0, K1, ws, out);
    }
  }
}

// Round 4
// 830.192 us; speedup vs baseline: 3.0840x; 3.0840x over previous
//
#include <hip/hip_runtime.h>
#include <math.h>

#define NPTS 4096
#define NCH  1024
#define HH 128
#define WW 128
#define SLICE (HH*WW)
#define PARTW 2048

struct WsPtrs {
  double* Hg;      // 27 doubles: H upper-tri (21) then g (6)
  float* state;    // [0..8]=R,[9..11]=t,[12]=lam,[13]=prev_cost,[14..22]=R_new,[23..25]=t_new
  float* p3d0;     // 3*NPTS SoA
  float* idx0x;    // NPTS (fallback path)
  float* idx0y;    // NPTS
  float* nidxx;    // NPTS clipped sample x at tentative state
  float* nidxy;    // NPTS
  float* np2;      // 2*NPTS interleaved
  float* best;     // 2*NPTS interleaved
  float* P12;      // 12*NPTS: per point r0[6], r1[6]
  float* coef;     // NPTS*16 float4: (wf, wgx, wgy, bitcast(pixel))
  float* part;     // 28*PARTW per-block partials
  float* feat0;    // [NCH][NPTS]
  float* feat0t;   // [NPTS][NCH]
  float* img1t;    // [SLICE][NCH]
};

__device__ inline float w3f(int k){ return (k==1)?2.f:((k==0||k==2)?1.f:0.f); }
__device__ inline float d3f(int k){ return (k==0)?-0.125f:((k==2)?0.125f:0.f); }

// ---- per-point projection + coefficient build: 1 thread per point, registers only ----
__global__ __launch_bounds__(256) void build_kernel(const float* __restrict__ K1, WsPtrs ws)
{
  const int n = blockIdx.x*256 + threadIdx.x;
  const float fx=K1[0], cx=K1[2], fy=K1[4], cy=K1[5];
  float sRt[12];
  #pragma unroll
  for (int k=0;k<12;k++) sRt[k]=ws.state[14+k];
  float px=ws.p3d0[n], py=ws.p3d0[NPTS+n], pz=ws.p3d0[2*NPTS+n];
  float X = sRt[0]*px + sRt[1]*py + sRt[2]*pz + sRt[9];
  float Y = sRt[3]*px + sRt[4]*py + sRt[5]*pz + sRt[10];
  float Z = sRt[6]*px + sRt[7]*py + sRt[8]*pz + sRt[11];
  float p2x = (fx*X + cx*Z)/Z;
  float p2y = (fy*Y + cy*Z)/Z;
  ws.np2[2*n]=p2x; ws.np2[2*n+1]=p2y;
  float xx = fminf(fmaxf(p2x*0.125f,0.f),(float)(WW-1));
  float yy = fminf(fmaxf(p2y*0.125f,0.f),(float)(HH-1));
  ws.nidxx[n]=xx; ws.nidxy[n]=yy;
  float a = (fx/Z)*0.125f;
  float b = (fy/Z)*0.125f;
  float c = ((-fx*X)/Z)/Z*0.125f;
  float d = ((-fy*Y)/Z)/Z*0.125f;
  float r0[6] = {a, 0.f, c, c*Y, a*Z - c*X, -a*Y};
  float r1[6] = {0.f, b, d, d*Y - b*Z, -d*X, b*X};
  #pragma unroll
  for (int k=0;k<6;k++){ ws.P12[n*12+k]=r0[k]; ws.P12[n*12+6+k]=r1[k]; }
  float x0f=floorf(xx), y0f=floorf(yy);
  float wx=xx-x0f, wy=yy-y0f;
  int xi=(int)x0f, yi=(int)y0f;
  int x1c=min(xi+1,WW-1), y1c=min(yi+1,HH-1);
  int c1 = x1c-(xi-1);    // window col of clamped x1 (1 or 2)
  int rr1 = y1c-(yi-1);   // window row of clamped y1 (1 or 2)
  float w00=(1.f-wx)*(1.f-wy), w10=wx*(1.f-wy), w01=(1.f-wx)*wy, w11=wx*wy;
  float4* cp = ((float4*)ws.coef) + (size_t)n*16;
  #pragma unroll
  for (int r=0;r<4;r++){
    float a1r=w3f(r), d1r=d3f(r);
    int k2=r-rr1+1;
    float a2r=w3f(k2), d2r=d3f(k2);
    float e1r=(r==1)?1.f:0.f, e2r=(r==rr1)?1.f:0.f;
    int sy=yi-1+r;
    bool iny=(sy>=0)&&(sy<HH);
    int ay=min(max(sy,0),HH-1);
    #pragma unroll
    for (int cc=0;cc<4;cc++){
      float a1c=w3f(cc), d1c=d3f(cc);
      int k2c=cc-c1+1;
      float a2c=w3f(k2c), d2c=d3f(k2c);
      float e1c=(cc==1)?1.f:0.f, e2c=(cc==c1)?1.f:0.f;
      int sx=xi-1+cc;
      bool inb = iny && (sx>=0) && (sx<WW);
      int ax=min(max(sx,0),WW-1);
      float wf  = e1r*(w00*e1c + w10*e2c) + e2r*(w01*e1c + w11*e2c);
      float wgx = inb ? (a1r*(w00*d1c + w10*d2c) + a2r*(w01*d1c + w11*d2c)) : 0.f;
      float wgy = inb ? (d1r*(w00*a1c + w10*a2c) + d2r*(w01*a1c + w11*a2c)) : 0.f;
      float4 cf; cf.x=wf; cf.y=wgx; cf.z=wgy; cf.w=__int_as_float(ay*WW+ax);
      cp[r*4+cc]=cf;
    }
  }
}

// ---- init kernel: matrices + p3d0 + idx0 only ----
__global__ __launch_bounds__(256) void prep_init_kernel(
    const float* __restrict__ pts2d, const float* __restrict__ pts3d,
    const float* __restrict__ qm, const float* __restrict__ rm,
    const float* __restrict__ K1, WsPtrs ws)
{
  const int t = threadIdx.x;
  if (t == 0) {
    double M[4][8];
    for (int i=0;i<4;i++) for (int j=0;j<4;j++){ M[i][j]=rm[i*4+j]; M[i][4+j]=(i==j)?1.0:0.0; }
    for (int k=0;k<4;k++){
      int p=k; double bv=fabs(M[k][k]);
      for (int i=k+1;i<4;i++){ double v=fabs(M[i][k]); if(v>bv){bv=v;p=i;} }
      if (p!=k) for (int j=0;j<8;j++){ double tmp=M[k][j]; M[k][j]=M[p][j]; M[p][j]=tmp; }
      double pv = M[k][k];
      for (int j=0;j<8;j++) M[k][j] /= pv;
      for (int i=0;i<4;i++) if (i!=k){
        double f2=M[i][k];
        for (int j=0;j<8;j++) M[i][j] -= f2*M[k][j];
      }
    }
    float rel[16];
    for (int i=0;i<4;i++) for (int j=0;j<4;j++){
      float s=0.f;
      for (int k=0;k<4;k++) s += qm[i*4+k]*(float)M[k][4+j];
      rel[i*4+j]=s;
    }
    for (int i=0;i<3;i++) for (int j=0;j<3;j++){ ws.state[i*3+j]=rel[i*4+j]; ws.state[14+i*3+j]=rel[i*4+j]; }
    for (int i=0;i<3;i++){ ws.state[9+i]=rel[i*4+3]; ws.state[23+i]=rel[i*4+3]; }
    ws.state[12] = 0.01f;
  }
  for (int i=0;i<16;i++){
    int n = t + i*256;
    float X=pts3d[n*3+0], Y=pts3d[n*3+1], Z=pts3d[n*3+2];
    float hx = rm[0]*X + rm[1]*Y + rm[2]*Z + rm[3];
    float hy = rm[4]*X + rm[5]*Y + rm[6]*Z + rm[7];
    float hz = rm[8]*X + rm[9]*Y + rm[10]*Z + rm[11];
    float hw = rm[12]*X + rm[13]*Y + rm[14]*Z + rm[15];
    ws.p3d0[n]=hx/hw; ws.p3d0[NPTS+n]=hy/hw; ws.p3d0[2*NPTS+n]=hz/hw;
    ws.idx0x[n]=pts2d[n*2+0]*0.125f;
    ws.idx0y[n]=pts2d[n*2+1]*0.125f;
  }
}

// ---- feat0 (iteration-invariant): one block per channel, writes [c][n] ----
__global__ __launch_bounds__(256) void feat0_kernel(
    const float* __restrict__ img0, const float* __restrict__ pts2d, WsPtrs ws)
{
  __shared__ __align__(16) float tile[SLICE];
  const int c = blockIdx.x;
  const int t = threadIdx.x;
  {
    const float4* g4 = reinterpret_cast<const float4*>(img0 + (size_t)c*SLICE);
    float4* t4 = reinterpret_cast<float4*>(tile);
    #pragma unroll
    for (int i=0;i<16;i++) t4[t + i*256] = g4[t + i*256];
  }
  __syncthreads();
  #pragma unroll
  for (int i=0;i<16;i++){
    int n = t + i*256;
    float x = pts2d[n*2+0]*0.125f, y = pts2d[n*2+1]*0.125f;
    float x0f=floorf(x), y0f=floorf(y);
    float wx=x-x0f, wy=y-y0f;
    int xi=min(max((int)x0f,0),WW-1);
    int yi=min(max((int)y0f,0),HH-1);
    int x1=min(xi+1,WW-1), y1=min(yi+1,HH-1);
    float f00=tile[yi*WW+xi], f10=tile[yi*WW+x1], f01=tile[y1*WW+xi], f11=tile[y1*WW+x1];
    ws.feat0[(size_t)c*NPTS + n] =
      f00*(1.f-wx)*(1.f-wy) + f10*wx*(1.f-wy) + f01*(1.f-wx)*wy + f11*wx*wy;
  }
}

// ---- generic 32x32 tiled transpose: src[R][Cc] -> dst[Cc][R] ----
__global__ __launch_bounds__(256) void transpose_kernel(
    const float* __restrict__ src, float* __restrict__ dst, int R, int Cc)
{
  __shared__ float tile[32][33];
  int bx = blockIdx.x*32, by = blockIdx.y*32;
  int tx = threadIdx.x & 31, ty = threadIdx.x >> 5;
  #pragma unroll
  for (int k=0;k<4;k++){
    int r = by + ty + k*8;
    tile[ty + k*8][tx] = src[(size_t)r*Cc + bx + tx];
  }
  __syncthreads();
  #pragma unroll
  for (int k=0;k<4;k++){
    int r = bx + ty + k*8;
    dst[(size_t)r*R + by + tx] = tile[tx][ty + k*8];
  }
}

// ---- main pass (fast path): 2 points per block, streaming coalesced gather ----
__global__ __launch_bounds__(256) void big_kernel(
    const float* __restrict__ img1t, const float* __restrict__ f0t, WsPtrs ws)
{
  __shared__ float4 scoef[2][16];
  __shared__ float sr[2][12];
  __shared__ float red6[4][6];
  __shared__ float sh6[6];
  const int b = blockIdx.x, t = threadIdx.x;
  const int n0 = b*2;
  if (t < 32) scoef[t>>4][t&15] = ((const float4*)ws.coef)[(size_t)n0*16 + t];
  else if (t < 56) { int q = t-32; sr[q/12][q%12] = ws.P12[(size_t)n0*12 + q]; }
  int kk=0, ll=0;
  if (t < 21){ int rem=t, k=0; while (rem >= 6-k){ rem -= 6-k; k++; } kk=k; ll=k+rem; }
  __syncthreads();
  float part28 = 0.f;
  const float* ip = img1t + 4*t;
  #pragma unroll
  for (int pt=0; pt<2; pt++){
    const int n = n0 + pt;
    float f10=0.f,f11=0.f,f12=0.f,f13=0.f;
    float gx0=0.f,gx1=0.f,gx2=0.f,gx3=0.f;
    float gy0=0.f,gy1=0.f,gy2=0.f,gy3=0.f;
    #pragma unroll
    for (int p=0;p<16;p++){
      float4 cf = scoef[pt][p];
      int pix = __float_as_int(cf.w);
      float4 v = *(const float4*)(ip + ((size_t)pix<<10));
      f10 = fmaf(cf.x, v.x, f10); f11 = fmaf(cf.x, v.y, f11);
      f12 = fmaf(cf.x, v.z, f12); f13 = fmaf(cf.x, v.w, f13);
      gx0 = fmaf(cf.y, v.x, gx0); gx1 = fmaf(cf.y, v.y, gx1);
      gx2 = fmaf(cf.y, v.z, gx2); gx3 = fmaf(cf.y, v.w, gx3);
      gy0 = fmaf(cf.z, v.x, gy0); gy1 = fmaf(cf.z, v.y, gy1);
      gy2 = fmaf(cf.z, v.z, gy2); gy3 = fmaf(cf.z, v.w, gy3);
    }
    float4 f0 = *(const float4*)(f0t + ((size_t)n<<10) + 4*t);
    float e0=f10-f0.x, e1=f11-f0.y, e2=f12-f0.z, e3=f13-f0.w;
    float v6[6];
    v6[0] = gx0*gx0 + gx1*gx1 + gx2*gx2 + gx3*gx3;
    v6[1] = gx0*gy0 + gx1*gy1 + gx2*gy2 + gx3*gy3;
    v6[2] = gy0*gy0 + gy1*gy1 + gy2*gy2 + gy3*gy3;
    v6[3] = e0*gx0 + e1*gx1 + e2*gx2 + e3*gx3;
    v6[4] = e0*gy0 + e1*gy1 + e2*gy2 + e3*gy3;
    v6[5] = e0*e0 + e1*e1 + e2*e2 + e3*e3;
    #pragma unroll
    for (int j=0;j<6;j++){
      float vv=v6[j];
      for (int off=32; off>0; off>>=1) vv += __shfl_down(vv, off, 64);
      v6[j]=vv;
    }
    int wave=t>>6, lane=t&63;
    if (lane==0){
      #pragma unroll
      for (int j=0;j<6;j++) red6[wave][j]=v6[j];
    }
    __syncthreads();
    if (t<6) sh6[t] = red6[0][t]+red6[1][t]+red6[2][t]+red6[3][t];
    __syncthreads();
    if (t<28){
      float m0=sh6[0], m1=sh6[1], m2=sh6[2], s0=sh6[3], s1=sh6[4], ss=sh6[5];
      const float* r0 = sr[pt];
      const float* r1 = sr[pt]+6;
      float ev;
      if (t<21)      ev = m0*r0[kk]*r0[ll] + m1*(r0[kk]*r1[ll] + r1[kk]*r0[ll]) + m2*r1[kk]*r1[ll];
      else if (t<27) ev = s0*r0[t-21] + s1*r1[t-21];
      else           ev = ss;
      part28 += ev;
    }
    __syncthreads();
  }
  if (t<28) ws.part[(size_t)t*PARTW + b] = part28;
}

// ---- fallback main pass (ws too small): round-1 proven two-phase ----
__global__ __launch_bounds__(256) void bigfb_kernel(
    const float* __restrict__ img0, const float* __restrict__ img1, WsPtrs ws)
{
  __shared__ __align__(16) float tile[SLICE];
  const int c = blockIdx.x;
  const int t = threadIdx.x;
  {
    const float4* g4 = reinterpret_cast<const float4*>(img1 + (size_t)c*SLICE);
    float4* t4 = reinterpret_cast<float4*>(tile);
    #pragma unroll
    for (int i=0;i<16;i++) t4[t + i*256] = g4[t + i*256];
  }
  __syncthreads();
  float f1a[16], gxa[16], gya[16];
  #pragma unroll
  for (int i=0;i<16;i++){
    int n = t + i*256;
    float x = ws.nidxx[n], y = ws.nidxy[n];
    float x0f = floorf(x), y0f = floorf(y);
    float wx = x - x0f, wy = y - y0f;
    int xi = (int)x0f, yi = (int)y0f;
    float v[4][4];
    if (xi>=1 && xi<=WW-3 && yi>=1 && yi<=HH-3) {
      int base = (yi-1)*WW + (xi-1);
      #pragma unroll
      for (int r=0;r<4;r++)
        #pragma unroll
        for (int cc=0;cc<4;cc++)
          v[r][cc] = tile[base + r*WW + cc];
    } else {
      #pragma unroll
      for (int r=0;r<4;r++){
        int ry = yi-1+r;
        bool okr = (ry>=0) && (ry<HH);
        int ryc = min(max(ry,0),HH-1);
        #pragma unroll
        for (int cc=0;cc<4;cc++){
          int rx = xi-1+cc;
          bool ok = okr && (rx>=0) && (rx<WW);
          int rxc = min(max(rx,0),WW-1);
          float val = tile[ryc*WW + rxc];
          v[r][cc] = ok ? val : 0.f;
        }
      }
    }
    float D1[4], D2[4], E0a[4], E1a[4];
    #pragma unroll
    for (int r=0;r<4;r++){ D1[r]=v[r][2]-v[r][0]; D2[r]=v[r][3]-v[r][1]; }
    #pragma unroll
    for (int cc=0;cc<4;cc++){ E0a[cc]=v[2][cc]-v[0][cc]; E1a[cc]=v[3][cc]-v[1][cc]; }
    float gx00 = D1[0] + 2.f*D1[1] + D1[2];
    float gx01 = D2[0] + 2.f*D2[1] + D2[2];
    float gx10 = D1[1] + 2.f*D1[2] + D1[3];
    float gx11 = D2[1] + 2.f*D2[2] + D2[3];
    float gy00 = E0a[0] + 2.f*E0a[1] + E0a[2];
    float gy01 = E0a[1] + 2.f*E0a[2] + E0a[3];
    float gy10 = E1a[0] + 2.f*E1a[1] + E1a[2];
    float gy11 = E1a[1] + 2.f*E1a[2] + E1a[3];
    float w00=(1.f-wx)*(1.f-wy), w10=wx*(1.f-wy), w01=(1.f-wx)*wy, w11=wx*wy;
    f1a[i] = w00*v[1][1] + w10*v[1][2] + w01*v[2][1] + w11*v[2][2];
    gxa[i] = 0.125f*(w00*gx00 + w10*gx01 + w01*gx10 + w11*gx11);
    gya[i] = 0.125f*(w00*gy00 + w10*gy01 + w01*gy10 + w11*gy11);
  }
  __syncthreads();
  {
    const float4* g4 = reinterpret_cast<const float4*>(img0 + (size_t)c*SLICE);
    float4* t4 = reinterpret_cast<float4*>(tile);
    #pragma unroll
    for (int i=0;i<16;i++) t4[t + i*256] = g4[t + i*256];
  }
  __syncthreads();
  float acc[28];
  #pragma unroll
  for (int a=0;a<28;a++) acc[a]=0.f;
  for (int i=0;i<16;i++){
    int n = t + i*256;
    float x = ws.idx0x[n], y = ws.idx0y[n];
    float x0f=floorf(x), y0f=floorf(y);
    float wx=x-x0f, wy=y-y0f;
    int xi=min(max((int)x0f,0),WW-1);
    int yi=min(max((int)y0f,0),HH-1);
    int x1=min(xi+1,WW-1), y1=min(yi+1,HH-1);
    float f00=tile[yi*WW+xi], f10=tile[yi*WW+x1], f01=tile[y1*WW+xi], f11=tile[y1*WW+x1];
    float feat0 = f00*(1.f-wx)*(1.f-wy) + f10*wx*(1.f-wy) + f01*(1.f-wx)*wy + f11*wx*wy;
    float e = f1a[i] - feat0;
    float gx = gxa[i], gy = gya[i];
    const float* r0 = ws.P12 + (size_t)n*12;
    const float* r1 = r0 + 6;
    float jv[6];
    #pragma unroll
    for (int k=0;k<6;k++) jv[k] = gx*r0[k] + gy*r1[k];
    int p=0;
    #pragma unroll
    for (int k=0;k<6;k++)
      #pragma unroll
      for (int l=k;l<6;l++)
        { acc[p] += jv[k]*jv[l]; p++; }
    #pragma unroll
    for (int k=0;k<6;k++) acc[21+k] += e*jv[k];
    acc[27] += e*e;
  }
  __syncthreads();
  #pragma unroll
  for (int a=0;a<28;a++){
    float vv=acc[a];
    for (int off=32; off>0; off>>=1) vv += __shfl_down(vv, off, 64);
    acc[a]=vv;
  }
  int wave = t>>6, lane = t&63;
  if (lane==0){
    #pragma unroll
    for (int a=0;a<28;a++) tile[wave*28+a]=acc[a];
  }
  __syncthreads();
  if (t<28){
    float s = tile[t]+tile[28+t]+tile[56+t]+tile[84+t];
    ws.part[(size_t)t*PARTW + c] = s;
    ws.part[(size_t)t*PARTW + 1024 + c] = 0.f;
  }
}

// ---- commit + LM solve + best/out (single block; per-point rebuild moved out) ----
__global__ __launch_bounds__(256) void solve_kernel(
    int force, WsPtrs ws, float* __restrict__ dout)
{
  const int t = threadIdx.x;
  __shared__ float red[4*28];
  __shared__ double stot[28];
  __shared__ int sacc;
  float loc[28];
  #pragma unroll
  for (int a=0;a<28;a++){
    const float* pa = ws.part + (size_t)a*PARTW;
    float s=0.f;
    #pragma unroll
    for (int k=0;k<8;k++) s += pa[t + k*256];
    loc[a]=s;
  }
  #pragma unroll
  for (int a=0;a<28;a++){
    float vv=loc[a];
    for (int off=32;off>0;off>>=1) vv += __shfl_down(vv,off,64);
    loc[a]=vv;
  }
  int wave=t>>6, lane=t&63;
  if (lane==0){
    #pragma unroll
    for (int a=0;a<28;a++) red[wave*28+a]=loc[a];
  }
  __syncthreads();
  if (t<28) stot[t] = (double)red[t]+(double)red[28+t]+(double)red[56+t]+(double)red[84+t];
  __syncthreads();
  if (t==0){
    float cost_new = (float)(stot[27] / (double)NPTS);
    int acc = force || (cost_new <= ws.state[13]);
    if (acc){
      ws.state[13]=cost_new;
      for (int k=0;k<9;k++) ws.state[k]=ws.state[14+k];
      for (int k=0;k<3;k++) ws.state[9+k]=ws.state[23+k];
      for (int a=0;a<27;a++) ws.Hg[a]=stot[a];
    }
    if (!force){
      float l = ws.state[12]*(acc?0.1f:10.f);
      ws.state[12]=fminf(fmaxf(l,1e-6f),100.f);
    }
    sacc=acc;
    // LM solve at committed state -> next tentative state in state[14..25]
    double M[6][7];
    {
      double Hf[6][6]; int p=0;
      for (int k=0;k<6;k++) for (int l=k;l<6;l++){ double v=ws.Hg[p++]; Hf[k][l]=v; Hf[l][k]=v; }
      double lam = (double)ws.state[12];
      for (int k=0;k<6;k++){
        for (int l=0;l<6;l++) M[k][l]=Hf[k][l];
        M[k][6]=ws.Hg[21+k];
      }
      for (int k=0;k<6;k++) M[k][k] = M[k][k] + (M[k][k] + 1e-9)*lam;
    }
    for (int k=0;k<6;k++){
      int pi=k; double bv=fabs(M[k][k]);
      for (int i=k+1;i<6;i++){ double v=fabs(M[i][k]); if(v>bv){bv=v;pi=i;} }
      if (pi!=k) for (int j=k;j<7;j++){ double tmp=M[k][j];M[k][j]=M[pi][j];M[pi][j]=tmp; }
      double pv=M[k][k];
      for (int i=k+1;i<6;i++){
        double f2=M[i][k]/pv;
        for (int j=k;j<7;j++) M[i][j]-=f2*M[k][j];
      }
    }
    double x[6];
    for (int k=5;k>=0;k--){
      double s=M[k][6];
      for (int j=k+1;j<6;j++) s-=M[k][j]*x[j];
      x[k]=s/M[k][k];
    }
    float dt0=(float)(-x[0]), dt1=(float)(-x[1]), dt2=(float)(-x[2]);
    float w0=(float)(-x[3]), w1=(float)(-x[4]), w2=(float)(-x[5]);
    float th2 = w0*w0+w1*w1+w2*w2;
    float th = sqrtf(fmaxf(th2, 1e-24f));
    float A_ = (th2 < 1e-16f) ? 1.f : (sinf(th)/th);
    float B_ = (th2 < 1e-16f) ? 0.5f : ((1.f - cosf(th)) / fmaxf(th2, 1e-24f));
    float Kx[9] = {0.f,-w2,w1,  w2,0.f,-w0,  -w1,w0,0.f};
    float K2[9];
    for (int i=0;i<3;i++) for (int j=0;j<3;j++){
      float s=0.f; for (int k=0;k<3;k++) s+=Kx[i*3+k]*Kx[k*3+j];
      K2[i*3+j]=s;
    }
    float dr[9];
    for (int i=0;i<9;i++) dr[i] = ((i%4==0)?1.f:0.f) + A_*Kx[i] + B_*K2[i];
    float Rn[9], tn[3];
    for (int i=0;i<3;i++) for (int j=0;j<3;j++){
      float s=0.f; for (int k=0;k<3;k++) s+=dr[i*3+k]*ws.state[k*3+j];
      Rn[i*3+j]=s;
    }
    for (int i=0;i<3;i++){
      float s=0.f; for (int k=0;k<3;k++) s+=dr[i*3+k]*ws.state[9+k];
      tn[i]=s+((i==0)?dt0:(i==1)?dt1:dt2);
    }
    for (int k=0;k<9;k++) ws.state[14+k]=Rn[k];
    for (int k=0;k<3;k++) ws.state[23+k]=tn[k];
  }
  __syncthreads();
  int acc=sacc;
  float2* best2=(float2*)ws.best;
  const float2* np22=(const float2*)ws.np2;
  float2* out2=(float2*)dout;
  #pragma unroll
  for (int i=0;i<16;i++){
    int n=t+i*256;
    if (acc) best2[n]=np22[n];
    out2[n]=best2[n];
  }
}

extern "C" void kernel_launch(void* const* d_in, const int* in_sizes, int n_in,
                              void* d_out, int out_size, void* d_ws, size_t ws_size,
                              hipStream_t stream) {
  (void)in_sizes; (void)n_in; (void)out_size;
  const float* img0  = (const float*)d_in[0];
  const float* img1  = (const float*)d_in[1];
  const float* pts2d = (const float*)d_in[2];
  const float* pts3d = (const float*)d_in[3];
  const float* qm    = (const float*)d_in[4];
  const float* rm    = (const float*)d_in[5];
  const float* K1    = (const float*)d_in[6];
  float* out = (float*)d_out;

  char* w = (char*)d_ws;
  WsPtrs ws;
  ws.Hg    = (double*)w;
  ws.state = (float*)(w + 256);
  float* f = (float*)(w + 512);
  ws.p3d0  = f; f += 3*NPTS;
  ws.idx0x = f; f += NPTS;
  ws.idx0y = f; f += NPTS;
  ws.nidxx = f; f += NPTS;
  ws.nidxy = f; f += NPTS;
  ws.np2   = f; f += 2*NPTS;
  ws.best  = f; f += 2*NPTS;
  ws.P12   = f; f += 12*NPTS;
  ws.coef  = f; f += 64*NPTS;
  ws.part  = f; f += 28*PARTW;
  ws.feat0  = f; f += (size_t)NCH*NPTS;
  ws.feat0t = f; f += (size_t)NCH*NPTS;
  ws.img1t  = f; f += (size_t)NCH*SLICE;
  size_t need = ((char*)f) - w;
  bool fast = (ws_size >= need);

  prep_init_kernel<<<1,256,0,stream>>>(pts2d, pts3d, qm, rm, K1, ws);
  build_kernel<<<NPTS/256,256,0,stream>>>(K1, ws);
  if (fast) {
    feat0_kernel<<<NCH,256,0,stream>>>(img0, pts2d, ws);
    transpose_kernel<<<dim3(NPTS/32, NCH/32),256,0,stream>>>(ws.feat0, ws.feat0t, NCH, NPTS);
    transpose_kernel<<<dim3(SLICE/32, NCH/32),256,0,stream>>>(img1, ws.img1t, NCH, SLICE);
    big_kernel<<<PARTW,256,0,stream>>>(ws.img1t, ws.feat0t, ws);
    solve_kernel<<<1,256,0,stream>>>(1, ws, out);
    for (int it=0; it<10; ++it){
      build_kernel<<<NPTS/256,256,0,stream>>>(K1, ws);
      big_kernel<<<PARTW,256,0,stream>>>(ws.img1t, ws.feat0t, ws);
      solve_kernel<<<1,256,0,stream>>>(0, ws, out);
    }
  } else {
    bigfb_kernel<<<NCH,256,0,stream>>>(img0, img1, ws);
    solve_kernel<<<1,256,0,stream>>>(1, ws, out);
    for (int it=0; it<10; ++it){
      build_kernel<<<NPTS/256,256,0,stream>>>(K1, ws);
      bigfb_kernel<<<NCH,256,0,stream>>>(img0, img1, ws);
      solve_kernel<<<1,256,0,stream>>>(0, ws, out);
    }
  }
}